// Round 6
// baseline (198.206 us; speedup 1.0000x reference)
//
#include <hip/hip_runtime.h>

#define NN   32768
#define HD   128
#define EE   524288
#define GG   256
#define EPG  2048
#define CCd  16
#define LLd  3

typedef short short8 __attribute__((ext_vector_type(8)));   // 8 bf16 = 4 VGPRs
typedef float f32x4 __attribute__((ext_vector_type(4)));

__device__ __forceinline__ unsigned short f2bf(float f) {
  unsigned u = __builtin_bit_cast(unsigned, f);
  return (unsigned short)((u + 0x7FFFu + ((u >> 16) & 1u)) >> 16);  // RNE
}
__device__ __forceinline__ unsigned bfpack(float a, float b) {
  return (unsigned)f2bf(a) | ((unsigned)f2bf(b) << 16);
}

// ---------------- prep: blocks [0,256) build per-graph M~ ; blocks [256,304) convert weights ----------------
__global__ __launch_bounds__(256) void prep_kernel(const int* __restrict__ src, const int* __restrict__ tgt,
                                                   const int* __restrict__ mask,
                                                   const float* __restrict__ Wn, const float* __restrict__ Wo,
                                                   const float* __restrict__ Wr, const float* __restrict__ bo,
                                                   unsigned* __restrict__ Mb, float* __restrict__ fin,
                                                   float* __restrict__ fout,
                                                   unsigned* __restrict__ Wnb, unsigned* __restrict__ Wob,
                                                   unsigned* __restrict__ Wrb, float* __restrict__ wsreg) {
  __shared__ unsigned Mi[2 * 128 * 64];   // 64 KB packed u16 counts [dir][t][s/2]
  const int tid = threadIdx.x;
  if (blockIdx.x >= GG) {                 // ---- weight-convert path ----
    int i = (blockIdx.x - GG) * 256 + tid;
    float4 a = *(const float4*)(Wn + (size_t)i * 4);
    float4 b = *(const float4*)(Wo + (size_t)i * 4);
    float4 c = *(const float4*)(Wr + (size_t)i * 4);
    *(uint2*)(Wnb + (size_t)i * 2) = make_uint2(bfpack(a.x, a.y), bfpack(a.z, a.w));
    *(uint2*)(Wob + (size_t)i * 2) = make_uint2(bfpack(b.x, b.y), bfpack(b.z, b.w));
    *(uint2*)(Wrb + (size_t)i * 2) = make_uint2(bfpack(c.x, c.y), bfpack(c.z, c.w));
    float s = fabsf(b.x) + fabsf(b.y) + fabsf(b.z) + fabsf(b.w);
    if (blockIdx.x == GG && tid < 96) {   // 384 bo elements
      float4 d = *(const float4*)(bo + tid * 4);
      s += fabsf(d.x) + fabsf(d.y) + fabsf(d.z) + fabsf(d.w);
    }
#pragma unroll
    for (int mk = 1; mk < 64; mk <<= 1) s += __shfl_xor(s, mk, 64);
    if ((tid & 63) == 0) atomicAdd(wsreg, s);
    return;
  }
  // ---- adjacency path ----
  const int g = blockIdx.x;
  uint4* Mi4 = (uint4*)Mi;
  for (int i = tid; i < 4096; i += 256) Mi4[i] = make_uint4(0, 0, 0, 0);
  __syncthreads();
  const int e0 = g * EPG;
#pragma unroll
  for (int i = 0; i < 8; ++i) {
    int e = e0 + i * 256 + tid;
    int t = tgt[e] & 127;
    int sl = src[e] & 127;
    int dir = (mask[e] != 0) ? 0 : 1;
    atomicAdd(&Mi[dir * 8192 + t * 64 + (sl >> 1)], 1u << ((sl & 1) * 16));
  }
  __syncthreads();
  const int t = tid >> 1, p = tid & 1;
  const int b0 = t * 64 + p * 32;
  unsigned nin = 0, nout = 0;
#pragma unroll 8
  for (int k = 0; k < 32; ++k) { unsigned v = Mi[b0 + ((k + t) & 31)]; nin += (v & 0xffffu) + (v >> 16); }
#pragma unroll 8
  for (int k = 0; k < 32; ++k) { unsigned v = Mi[8192 + b0 + ((k + t) & 31)]; nout += (v & 0xffffu) + (v >> 16); }
  nin += __shfl_xor((int)nin, 1);
  nout += __shfl_xor((int)nout, 1);
  unsigned dg = nin + nout;
  float inv = 1.0f / (float)(dg > 0 ? dg : 1);
  if (p == 0) { fin[g * 128 + t] = (float)nin * inv; fout[g * 128 + t] = (float)nout * inv; }
#pragma unroll
  for (int dir = 0; dir < 2; ++dir) {
    int base = dir * 8192 + b0;
#pragma unroll 8
    for (int k = 0; k < 32; ++k) {
      int kk = (k + t) & 31;
      unsigned v = Mi[base + kk];
      Mb[(size_t)g * 16384 + base + kk] = bfpack((float)(v & 0xffffu) * inv, (float)(v >> 16) * inv);
    }
  }
}

// ---------------- fully fused per-graph network, v3: 1024 threads / 16 waves ----------------
// wave = 8h + w: h = column-half (ct in [4h,4h+4)), w = t-tile (rows [16w,16w+16)).
// Y-phase: wave computes op=h's Y for cols [16w,16w+16). LN via (sum, sum-sq) LDS exchange.
#define SSTR 136   // scratch stride in shorts
#define YSTR 40    // ys stride in shorts
__global__ __launch_bounds__(1024) void fused_kernel(
    const float* __restrict__ x, const unsigned short* __restrict__ Mb,
    const unsigned short* __restrict__ Wnb, const unsigned short* __restrict__ Wob,
    const unsigned short* __restrict__ Wrb,
    const float* __restrict__ bn, const float* __restrict__ bo,
    const float* __restrict__ fin, const float* __restrict__ fout,
    const float* __restrict__ lng, const float* __restrict__ lnb,
    const float* __restrict__ s,
    const float* __restrict__ flng, const float* __restrict__ flnb,
    const float* __restrict__ linw, const float* __restrict__ bias,
    float* __restrict__ out, float* __restrict__ l1g) {
  __shared__ unsigned short scratch[128 * SSTR];  // 34.0 KB  h [t][f] bf16
  __shared__ unsigned short ys[2 * 128 * YSTR];   // 20.0 KB  Y chunk [op][c][s_local]
  __shared__ unsigned short sTs[16 * SSTR];       //  4.3 KB  s^T [c][t] bf16
  __shared__ float pexch[128][4];                 //  2.0 KB  [t][{sum0,sq0,sum1,sq1}]
  __shared__ float colsumS[CCd];
  __shared__ float xcs[CCd], axcs[CCd], msk[CCd];

  const int g = blockIdx.x;
  const int tid = threadIdx.x;
  const int wave = tid >> 6;
  const int h = wave >> 3;
  const int w = wave & 7;
  const int lane = tid & 63;
  const int m = lane & 15;
  const int q = lane >> 4;
  const unsigned short* Mg = Mb + (size_t)g * 32768;       // [op][t][s]
  unsigned* scratch32 = (unsigned*)scratch;

  // ---- init: x -> scratch [t][f] bf16 ----
  {
    const float4* xg = (const float4*)(x + (size_t)g * 16384);
#pragma unroll
    for (int i = 0; i < 4; ++i) {
      int flat = i * 1024 + tid;             // 4096 float4s
      int t = flat >> 5, f = (flat & 31) << 2;
      float4 v = xg[flat];
      int w0 = (t * SSTR + f) >> 1;
      scratch32[w0] = bfpack(v.x, v.y);
      scratch32[w0 + 1] = bfpack(v.z, v.w);
    }
    if (tid < 512) {
      int t = tid >> 2, c0 = (tid & 3) << 2;
      float4 v = *(const float4*)(s + (size_t)g * 2048 + t * 16 + c0);
      sTs[(c0 + 0) * SSTR + t] = f2bf(v.x);
      sTs[(c0 + 1) * SSTR + t] = f2bf(v.y);
      sTs[(c0 + 2) * SSTR + t] = f2bf(v.z);
      sTs[(c0 + 3) * SSTR + t] = f2bf(v.w);
    }
    if (tid < CCd) {
      float cs = 0.f;
      for (int tt = 0; tt < 128; ++tt) cs += s[(size_t)g * 2048 + tt * 16 + tid];
      colsumS[tid] = cs;
    }
  }
  // per-lane row constants (rows T = 16w + q*4 + r)
  float fivr[4], fovr[4];
#pragma unroll
  for (int r = 0; r < 4; ++r) {
    fivr[r] = fin[g * 128 + w * 16 + q * 4 + r];
    fovr[r] = fout[g * 128 + w * 16 + q * 4 + r];
  }
  __syncthreads();

  for (int L = 0; L < LLd; ++L) {
    const unsigned short* WnL = Wnb + (size_t)L * 16384;
    const unsigned short* WoL = Wob + (size_t)L * 16384;
    const unsigned short* WrL = Wrb + (size_t)L * 16384;
    const unsigned short* Wh = h ? WoL : WnL;
    // Y-phase B-frags: our op's W col-slice c = 16w+m, all 4 k-chunks (16 VGPRs)
    short8 wf[4];
#pragma unroll
    for (int ks = 0; ks < 4; ++ks)
      wf[ks] = *(const short8*)(Wh + (size_t)(w * 16 + m) * 128 + ks * 32 + q * 8);

    f32x4 pre[4];
#pragma unroll
    for (int ct = 0; ct < 4; ++ct) pre[ct] = (f32x4){0.f, 0.f, 0.f, 0.f};

    // --- R-phase: pre += h * Wr^T (A own rows LDS, B global/L2) ---
#pragma unroll
    for (int ks = 0; ks < 4; ++ks) {
      short8 a = *(const short8*)&scratch[(w * 16 + m) * SSTR + ks * 32 + q * 8];
#pragma unroll
      for (int ct = 0; ct < 4; ++ct) {
        short8 b = *(const short8*)(WrL + (size_t)((h * 4 + ct) * 16 + m) * 128 + ks * 32 + q * 8);
        pre[ct] = __builtin_amdgcn_mfma_f32_16x16x32_bf16(a, b, pre[ct], 0, 0, 0);
      }
    }

    // --- s-chunk loop ---
    for (int sc = 0; sc < 4; ++sc) {
      // prefetch consume-phase M~ frags (global) early
      short8 am0 = *(const short8*)(Mg + (size_t)(w * 16 + m) * 128 + sc * 32 + q * 8);
      short8 am1 = *(const short8*)(Mg + 16384 + (size_t)(w * 16 + m) * 128 + sc * 32 + q * 8);
      f32x4 ya0 = (f32x4){0.f, 0.f, 0.f, 0.f}, ya1 = (f32x4){0.f, 0.f, 0.f, 0.f};
#pragma unroll
      for (int ks = 0; ks < 4; ++ks) {
        short8 a0 = *(const short8*)&scratch[(sc * 32 + m) * SSTR + ks * 32 + q * 8];
        short8 a1 = *(const short8*)&scratch[(sc * 32 + 16 + m) * SSTR + ks * 32 + q * 8];
        ya0 = __builtin_amdgcn_mfma_f32_16x16x32_bf16(a0, wf[ks], ya0, 0, 0, 0);
        ya1 = __builtin_amdgcn_mfma_f32_16x16x32_bf16(a1, wf[ks], ya1, 0, 0, 0);
      }
      {
        const int ybase = h * 128 * YSTR + (w * 16 + m) * YSTR + q * 4;
#pragma unroll
        for (int r = 0; r < 4; ++r) ys[ybase + r] = f2bf(ya0[r]);
#pragma unroll
        for (int r = 0; r < 4; ++r) ys[ybase + 16 + r] = f2bf(ya1[r]);
      }
      __syncthreads();
      // consume: pre += M~op[t-rows, chunk] * Ychunk  (B from ys, our 4 ct tiles)
#pragma unroll
      for (int ct = 0; ct < 4; ++ct) {
        short8 b0 = *(const short8*)&ys[((h * 4 + ct) * 16 + m) * YSTR + q * 8];
        short8 b1 = *(const short8*)&ys[128 * YSTR + ((h * 4 + ct) * 16 + m) * YSTR + q * 8];
        pre[ct] = __builtin_amdgcn_mfma_f32_16x16x32_bf16(am0, b0, pre[ct], 0, 0, 0);
        pre[ct] = __builtin_amdgcn_mfma_f32_16x16x32_bf16(am1, b1, pre[ct], 0, 0, 0);
      }
      if (sc < 3) __syncthreads();
    }

    // --- epilogue: bias mix; LN via (sum, sumsq) exchange; ReLU -> scratch ---
    float bnv[4], bov[4], gv[4], bv[4];
#pragma unroll
    for (int ct = 0; ct < 4; ++ct) {
      int c = L * 128 + (h * 4 + ct) * 16 + m;
      bnv[ct] = bn[c]; bov[ct] = bo[c]; gv[ct] = lng[c]; bv[ct] = lnb[c];
    }
    float v[4][4];
#pragma unroll
    for (int r = 0; r < 4; ++r) {
      float sum = 0.f, sq = 0.f;
#pragma unroll
      for (int ct = 0; ct < 4; ++ct) {
        float vv = pre[ct][r] + fivr[r] * bnv[ct] + fovr[r] * bov[ct];
        v[r][ct] = vv;
        sum += vv; sq += vv * vv;
      }
      sum += __shfl_xor(sum, 1); sq += __shfl_xor(sq, 1);
      sum += __shfl_xor(sum, 2); sq += __shfl_xor(sq, 2);
      sum += __shfl_xor(sum, 4); sq += __shfl_xor(sq, 4);
      sum += __shfl_xor(sum, 8); sq += __shfl_xor(sq, 8);
      if (m == 0) {
        pexch[w * 16 + q * 4 + r][h * 2] = sum;
        pexch[w * 16 + q * 4 + r][h * 2 + 1] = sq;
      }
    }
    __syncthreads();
#pragma unroll
    for (int r = 0; r < 4; ++r) {
      const int tl = w * 16 + q * 4 + r;
      float4 px = *(const float4*)&pexch[tl][0];
      float mu = (px.x + px.z) * (1.0f / 128.0f);
      float var = (px.y + px.w) * (1.0f / 128.0f) - mu * mu;
      float rstd = rsqrtf(fmaxf(var, 0.0f) + 1e-5f);
#pragma unroll
      for (int ct = 0; ct < 4; ++ct) {
        float o = fmaxf((v[r][ct] - mu) * rstd * gv[ct] + bv[ct], 0.0f);
        scratch[tl * SSTR + (h * 4 + ct) * 16 + m] = f2bf(o);
      }
    }
    __syncthreads();
  }

  // ---- pool (waves h=0): pooled[c][fo] = sum_t s[t][c]*h[t][fo]; wave w owns fo-tile w ----
  float* pooledS = (float*)ys;   // 16 x 132 fp32
  if (h == 0) {
    f32x4 pl = (f32x4){0.f, 0.f, 0.f, 0.f};
#pragma unroll
    for (int ks = 0; ks < 4; ++ks) {
      short8 a = *(const short8*)&sTs[m * SSTR + ks * 32 + q * 8];
      short8 b;
#pragma unroll
      for (int j = 0; j < 8; ++j)
        b[j] = (short)scratch[(ks * 32 + q * 8 + j) * SSTR + w * 16 + m];
      pl = __builtin_amdgcn_mfma_f32_16x16x32_bf16(a, b, pl, 0, 0, 0);
    }
#pragma unroll
    for (int r = 0; r < 4; ++r) pooledS[(q * 4 + r) * 132 + w * 16 + m] = pl[r];
  }
  __syncthreads();

  // ---- final LN + lin + mask (threads 0..255) ----
  if (tid < 256) {
    const int c = tid >> 4;
    const int j0 = (tid & 15) << 3;
    float v[8];
#pragma unroll
    for (int jj = 0; jj < 8; ++jj) v[jj] = pooledS[c * 132 + j0 + jj];
    float sum = 0.f;
#pragma unroll
    for (int jj = 0; jj < 8; ++jj) sum += v[jj];
#pragma unroll
    for (int mk = 1; mk < 16; mk <<= 1) sum += __shfl_xor(sum, mk, 64);
    float mu = sum * (1.0f / 128.0f);
    float sq = 0.f;
#pragma unroll
    for (int jj = 0; jj < 8; ++jj) { float d = v[jj] - mu; sq += d * d; }
#pragma unroll
    for (int mk = 1; mk < 16; mk <<= 1) sq += __shfl_xor(sq, mk, 64);
    float rstd = rsqrtf(sq * (1.0f / 128.0f) + 1e-5f);
    float dot = 0.f;
#pragma unroll
    for (int jj = 0; jj < 8; ++jj) {
      float nv = (v[jj] - mu) * rstd * flng[j0 + jj] + flnb[j0 + jj];
      dot += nv * linw[j0 + jj];
    }
#pragma unroll
    for (int mk = 1; mk < 16; mk <<= 1) dot += __shfl_xor(dot, mk, 64);
    if ((tid & 15) == 0) {
      float cm = (colsumS[c] > 0.f) ? 1.0f : 0.0f;
      float xcv = dot * cm;
      out[257 + g * CCd + c] = xcv;
      xcs[c] = xcv; axcs[c] = fabsf(xcv); msk[c] = cm;
    }
  }
  __syncthreads();
  if (tid == 0) {
    float so = 0.f, sa = 0.f, sd = 0.f;
#pragma unroll
    for (int k = 0; k < CCd; ++k) { so += xcs[k]; sa += axcs[k]; sd += msk[k] + 1e-7f; }
    out[g] = so + bias[0];
    l1g[g] = sa / sd;
  }
}

// ---------------- combine: losses = 0.01*reg + 0.01*mean_g(l1g) ----------------
__global__ __launch_bounds__(256) void combine_kernel(const float* __restrict__ l1g, const float* __restrict__ wsreg,
                                                      float* __restrict__ outp) {
  const int tid = threadIdx.x;
  float s2 = l1g[tid];
#pragma unroll
  for (int mk = 1; mk < 64; mk <<= 1) s2 += __shfl_xor(s2, mk, 64);
  __shared__ float rs2[4];
  if ((tid & 63) == 0) rs2[tid >> 6] = s2;
  __syncthreads();
  if (tid == 0) {
    float l1 = (rs2[0] + rs2[1] + rs2[2] + rs2[3]) * (1.0f / GG);
    outp[0] = 0.01f * wsreg[0] + 0.01f * l1;
  }
}

extern "C" void kernel_launch(void* const* d_in, const int* in_sizes, int n_in,
                              void* d_out, int out_size, void* d_ws, size_t ws_size,
                              hipStream_t stream) {
  (void)in_sizes; (void)n_in; (void)out_size; (void)ws_size;
  const float* x    = (const float*)d_in[0];
  const int*   ei   = (const int*)d_in[1];
  const int*   mask = (const int*)d_in[2];
  const float* s    = (const float*)d_in[3];
  const float* Wn   = (const float*)d_in[5];
  const float* bn   = (const float*)d_in[6];
  const float* Wo   = (const float*)d_in[7];
  const float* bo   = (const float*)d_in[8];
  const float* Wr   = (const float*)d_in[9];
  const float* lng  = (const float*)d_in[10];
  const float* lnb  = (const float*)d_in[11];
  const float* flng = (const float*)d_in[12];
  const float* flnb = (const float*)d_in[13];
  const float* linw = (const float*)d_in[14];
  const float* bias = (const float*)d_in[15];
  float* out = (float*)d_out;

  char* ws = (char*)d_ws;
  size_t off = 0;
  auto alloc = [&](size_t b) { char* p = ws + off; off += (b + 255) & ~(size_t)255; return p; };
  unsigned short* Mbuf = (unsigned short*)alloc((size_t)GG * 2 * 128 * 128 * 2);  // 16.8 MB
  float* fin    = (float*)alloc((size_t)NN * 4);
  float* fout   = (float*)alloc((size_t)NN * 4);
  unsigned short* Wnb = (unsigned short*)alloc((size_t)LLd * HD * HD * 2);
  unsigned short* Wob = (unsigned short*)alloc((size_t)LLd * HD * HD * 2);
  unsigned short* Wrb = (unsigned short*)alloc((size_t)LLd * HD * HD * 2);
  float* l1g    = (float*)alloc((size_t)GG * 4);
  float* wsreg  = (float*)alloc(256);

  const int* srcA = ei;
  const int* tgtA = ei + EE;

  hipMemsetAsync(wsreg, 0, 4, stream);
  prep_kernel<<<GG + 48, 256, 0, stream>>>(srcA, tgtA, mask, Wn, Wo, Wr, bo,
      (unsigned*)Mbuf, fin, fout, (unsigned*)Wnb, (unsigned*)Wob, (unsigned*)Wrb, wsreg);
  fused_kernel<<<GG, 1024, 0, stream>>>(x, Mbuf, Wnb, Wob, Wrb, bn, bo, fin, fout,
                                        lng, lnb, s, flng, flnb, linw, bias, out, l1g);
  combine_kernel<<<1, 256, 0, stream>>>(l1g, wsreg, out + 256);
}